// Round 9
// baseline (295.536 us; speedup 1.0000x reference)
//
#include <hip/hip_runtime.h>

// WaveNet-ish: 10 stacked causal dilated conv1d (1ch, k=2, dil=2^i), then 1x1 -> 256ch.
// B=16, T=16384, receptive shrink 1023, final length 15361, classes 256.
//
// Single fat kernel: 256 blocks (one per CU; (b, t-tile of 1024)), 1024 threads.
// Prologue (stage x + 10 layers in LDS) runs ONCE per tile, then 4 subgroups of
// 256 threads stream all 256 channels (64 each) as aligned float4 NON-TEMPORAL
// stores (bypass L2/MALL allocation — pure write stream, read exactly once later).
// NOTE: __builtin_nontemporal_store needs a NATIVE vector type, not HIP float4.

#define NL     10
#define B_     16
#define T_     16384
#define SHRINK 1023          // sum_{i<10} 2^i
#define LFIN   15361         // T_ - SHRINK
#define NC     256
#define TO     1024          // h outputs per tile
#define TILES  16            // LFIN = 15*1024 + 1
#define NIN_MAX 2047         // TO + SHRINK

typedef float f32x4 __attribute__((ext_vector_type(4)));

__device__ __forceinline__ void nt_store4(float* p, float a, float b, float c, float d) {
    f32x4 v = {a, b, c, d};
    __builtin_nontemporal_store(v, reinterpret_cast<f32x4*>(p));
}

__global__ __launch_bounds__(1024) void wn_fat_nt(
    const float* __restrict__ x,      // [B][T]
    const float* __restrict__ cw,     // [NL][2]
    const float* __restrict__ cb,     // [NL]
    const float* __restrict__ ow,     // [NC]
    const float* __restrict__ ob,     // [NC]
    float* __restrict__ out)          // [B][NC][LFIN]
{
    __shared__ float lds[2048];
    const int bid  = blockIdx.x;      // 0..255
    const int b    = bid >> 4;
    const int tile = bid & 15;
    const int s0   = tile * TO;
    const int tid  = threadIdx.x;

    int n_in = T_ - s0; if (n_in > NIN_MAX) n_in = NIN_MAX;

    // ---- stage x tile (coalesced, 2 elems/thread) ----
    {
        int i0 = tid, i1 = tid + 1024;
        if (i0 < n_in) lds[i0] = x[b * T_ + s0 + i0];
        if (i1 < n_in) lds[i1] = x[b * T_ + s0 + i1];
    }
    __syncthreads();

    // ---- 10 dilated conv layers in LDS (2 elems/thread) ----
    int cur = n_in;
    #pragma unroll
    for (int i = 0; i < NL; ++i) {
        const int d   = 1 << i;
        const int len = cur - d;
        const float w0 = cw[2 * i], w1 = cw[2 * i + 1], bbv = cb[i];
        float v0 = 0.f, v1 = 0.f;
        const int t0 = tid, t1 = tid + 1024;
        const bool p0 = t0 < len, p1 = t1 < len;
        if (p0) v0 = fmaxf(fmaf(w0, lds[t0], fmaf(w1, lds[t0 + d], bbv)), 0.f);
        if (p1) v1 = fmaxf(fmaf(w0, lds[t1], fmaf(w1, lds[t1 + d], bbv)), 0.f);
        __syncthreads();
        if (p0) lds[t0] = v0;
        if (p1) lds[t1] = v1;
        __syncthreads();
        cur = len;
    }

    int n_out = LFIN - s0; if (n_out > TO) n_out = TO;   // 1024, or 1 for tile 15

    const int ts  = tid & 255;        // lane-in-subgroup
    const int sub = tid >> 8;         // 0..3 -> channels [64*sub, 64*sub+64)
    const int cbase = sub << 6;

    // this thread's 8 h values (window covers all 4 alignment cases)
    float hv[8];
    {
        float4 a = *reinterpret_cast<const float4*>(&lds[4 * ts]);
        float4 q = *reinterpret_cast<const float4*>(&lds[4 * ts + 4]);  // <=1027 < 2048
        hv[0] = a.x; hv[1] = a.y; hv[2] = a.z; hv[3] = a.w;
        hv[4] = q.x; hv[5] = q.y; hv[6] = q.z; hv[7] = q.w;
    }

    if (n_out == TO) {
        // base element index of row (b, cbase) at column s0.
        // row%4 == c%4 (LFIN%4==1, s0%4==0) -> head length al0(q) = (4-q)&3, q=c%4.
        size_t base = ((size_t)(b * NC + cbase)) * LFIN + s0;
        #pragma unroll 4
        for (int g = 0; g < 16; ++g) {
            const int c = cbase + 4 * g;
            const float4 w4 = *reinterpret_cast<const float4*>(&ow[c]);  // uniform
            const float4 b4 = *reinterpret_cast<const float4*>(&ob[c]);

            // ---- q = 0: al0=0, nv=256, rem=0 ----
            {
                const float w = w4.x, bs = b4.x;
                nt_store4(&out[base + 4 * ts],
                          fmaf(w, hv[0], bs), fmaf(w, hv[1], bs),
                          fmaf(w, hv[2], bs), fmaf(w, hv[3], bs));
            }
            // ---- q = 1: al0=3, nv=255, rem=1 ----
            {
                const float w = w4.y, bs = b4.y;
                const size_t bq = base + LFIN;
                if (ts < 3)   out[bq + ts] = fmaf(w, lds[ts], bs);
                if (ts < 255) {
                    nt_store4(&out[bq + 3 + 4 * ts],
                              fmaf(w, hv[3], bs), fmaf(w, hv[4], bs),
                              fmaf(w, hv[5], bs), fmaf(w, hv[6], bs));
                }
                if (ts < 1)   out[bq + 1023 + ts] = fmaf(w, lds[1023 + ts], bs);
            }
            // ---- q = 2: al0=2, nv=255, rem=2 ----
            {
                const float w = w4.z, bs = b4.z;
                const size_t bq = base + 2 * (size_t)LFIN;
                if (ts < 2)   out[bq + ts] = fmaf(w, lds[ts], bs);
                if (ts < 255) {
                    nt_store4(&out[bq + 2 + 4 * ts],
                              fmaf(w, hv[2], bs), fmaf(w, hv[3], bs),
                              fmaf(w, hv[4], bs), fmaf(w, hv[5], bs));
                }
                if (ts < 2)   out[bq + 1022 + ts] = fmaf(w, lds[1022 + ts], bs);
            }
            // ---- q = 3: al0=1, nv=255, rem=3 ----
            {
                const float w = w4.w, bs = b4.w;
                const size_t bq = base + 3 * (size_t)LFIN;
                if (ts < 1)   out[bq + ts] = fmaf(w, lds[ts], bs);
                if (ts < 255) {
                    nt_store4(&out[bq + 1 + 4 * ts],
                              fmaf(w, hv[1], bs), fmaf(w, hv[2], bs),
                              fmaf(w, hv[3], bs), fmaf(w, hv[4], bs));
                }
                if (ts < 3)   out[bq + 1021 + ts] = fmaf(w, lds[1021 + ts], bs);
            }
            base += 4 * (size_t)LFIN;
        }
    } else {
        // last tile: n_out == 1
        #pragma unroll 1
        for (int k = 0; k < 64; ++k) {
            const int c = cbase + k;
            const float w = ow[c], bs = ob[c];
            const size_t base = ((size_t)(b * NC + c)) * LFIN + s0;
            if (ts < n_out) out[base + ts] = fmaf(w, lds[ts], bs);
        }
    }
}

extern "C" void kernel_launch(void* const* d_in, const int* in_sizes, int n_in,
                              void* d_out, int out_size, void* d_ws, size_t ws_size,
                              hipStream_t stream) {
    const float* x  = (const float*)d_in[0];
    const float* cw = (const float*)d_in[1];
    const float* cb = (const float*)d_in[2];
    const float* ow = (const float*)d_in[3];
    const float* ob = (const float*)d_in[4];
    float* out = (float*)d_out;
    (void)d_ws; (void)ws_size; (void)in_sizes; (void)n_in; (void)out_size;

    wn_fat_nt<<<B_ * TILES, 1024, 0, stream>>>(x, cw, cb, ow, ob, out);
}

// Round 12
// 265.039 us; speedup vs baseline: 1.1151x; 1.1151x over previous
//
#include <hip/hip_runtime.h>

// WaveNet-ish: 10 stacked causal dilated conv1d (1ch, k=2, dil=2^i), then 1x1 -> 256ch.
// B=16, T=16384, receptive shrink 1023, final length 15361, classes 256.
//
// Single fat kernel: 256 blocks (one per CU; (b, t-tile of 1024)), 1024 threads.
// Prologue (stage x + 10 layers in LDS) runs ONCE per tile, then 4 subgroups of
// 256 threads stream all 256 channels (64 each) as aligned float4 stores with
// compile-time head/middle/tail split (c%4 static within the unrolled group).
// NOTE: non-temporal stores measured WORSE (R9: +9 µs normalized) — plain
// stores keep L2 write-combining and match the fill kernel's 6.5 TB/s path.

#define NL     10
#define B_     16
#define T_     16384
#define SHRINK 1023          // sum_{i<10} 2^i
#define LFIN   15361         // T_ - SHRINK
#define NC     256
#define TO     1024          // h outputs per tile
#define TILES  16            // LFIN = 15*1024 + 1
#define NIN_MAX 2047         // TO + SHRINK

__global__ __launch_bounds__(1024) void wn_fat(
    const float* __restrict__ x,      // [B][T]
    const float* __restrict__ cw,     // [NL][2]
    const float* __restrict__ cb,     // [NL]
    const float* __restrict__ ow,     // [NC]
    const float* __restrict__ ob,     // [NC]
    float* __restrict__ out)          // [B][NC][LFIN]
{
    __shared__ float lds[2048];
    const int bid  = blockIdx.x;      // 0..255
    const int b    = bid >> 4;
    const int tile = bid & 15;
    const int s0   = tile * TO;
    const int tid  = threadIdx.x;

    int n_in = T_ - s0; if (n_in > NIN_MAX) n_in = NIN_MAX;

    // ---- stage x tile (coalesced, 2 elems/thread) ----
    {
        int i0 = tid, i1 = tid + 1024;
        if (i0 < n_in) lds[i0] = x[b * T_ + s0 + i0];
        if (i1 < n_in) lds[i1] = x[b * T_ + s0 + i1];
    }
    __syncthreads();

    // ---- 10 dilated conv layers in LDS (2 elems/thread) ----
    int cur = n_in;
    #pragma unroll
    for (int i = 0; i < NL; ++i) {
        const int d   = 1 << i;
        const int len = cur - d;
        const float w0 = cw[2 * i], w1 = cw[2 * i + 1], bbv = cb[i];
        float v0 = 0.f, v1 = 0.f;
        const int t0 = tid, t1 = tid + 1024;
        const bool p0 = t0 < len, p1 = t1 < len;
        if (p0) v0 = fmaxf(fmaf(w0, lds[t0], fmaf(w1, lds[t0 + d], bbv)), 0.f);
        if (p1) v1 = fmaxf(fmaf(w0, lds[t1], fmaf(w1, lds[t1 + d], bbv)), 0.f);
        __syncthreads();
        if (p0) lds[t0] = v0;
        if (p1) lds[t1] = v1;
        __syncthreads();
        cur = len;
    }

    int n_out = LFIN - s0; if (n_out > TO) n_out = TO;   // 1024, or 1 for tile 15

    const int ts  = tid & 255;        // lane-in-subgroup
    const int sub = tid >> 8;         // 0..3 -> channels [64*sub, 64*sub+64)
    const int cbase = sub << 6;

    // this thread's 8 h values (window covers all 4 alignment cases)
    float hv[8];
    {
        float4 a = *reinterpret_cast<const float4*>(&lds[4 * ts]);
        float4 q = *reinterpret_cast<const float4*>(&lds[4 * ts + 4]);  // <=1027 < 2048
        hv[0] = a.x; hv[1] = a.y; hv[2] = a.z; hv[3] = a.w;
        hv[4] = q.x; hv[5] = q.y; hv[6] = q.z; hv[7] = q.w;
    }

    if (n_out == TO) {
        // base element index of row (b, cbase) at column s0.
        // row%4 == c%4 (LFIN%4==1, s0%4==0) -> head length al0(q) = (4-q)&3, q=c%4.
        size_t base = ((size_t)(b * NC + cbase)) * LFIN + s0;
        #pragma unroll 4
        for (int g = 0; g < 16; ++g) {
            const int c = cbase + 4 * g;
            const float4 w4 = *reinterpret_cast<const float4*>(&ow[c]);  // uniform
            const float4 b4 = *reinterpret_cast<const float4*>(&ob[c]);

            // ---- q = 0: al0=0, nv=256, rem=0 ----
            {
                const float w = w4.x, bs = b4.x;
                float4 v = make_float4(fmaf(w, hv[0], bs), fmaf(w, hv[1], bs),
                                       fmaf(w, hv[2], bs), fmaf(w, hv[3], bs));
                *reinterpret_cast<float4*>(&out[base + 4 * ts]) = v;
            }
            // ---- q = 1: al0=3, nv=255, rem=1 ----
            {
                const float w = w4.y, bs = b4.y;
                const size_t bq = base + LFIN;
                if (ts < 3)   out[bq + ts] = fmaf(w, lds[ts], bs);
                if (ts < 255) {
                    float4 v = make_float4(fmaf(w, hv[3], bs), fmaf(w, hv[4], bs),
                                           fmaf(w, hv[5], bs), fmaf(w, hv[6], bs));
                    *reinterpret_cast<float4*>(&out[bq + 3 + 4 * ts]) = v;
                }
                if (ts < 1)   out[bq + 1023 + ts] = fmaf(w, lds[1023 + ts], bs);
            }
            // ---- q = 2: al0=2, nv=255, rem=2 ----
            {
                const float w = w4.z, bs = b4.z;
                const size_t bq = base + 2 * (size_t)LFIN;
                if (ts < 2)   out[bq + ts] = fmaf(w, lds[ts], bs);
                if (ts < 255) {
                    float4 v = make_float4(fmaf(w, hv[2], bs), fmaf(w, hv[3], bs),
                                           fmaf(w, hv[4], bs), fmaf(w, hv[5], bs));
                    *reinterpret_cast<float4*>(&out[bq + 2 + 4 * ts]) = v;
                }
                if (ts < 2)   out[bq + 1022 + ts] = fmaf(w, lds[1022 + ts], bs);
            }
            // ---- q = 3: al0=1, nv=255, rem=3 ----
            {
                const float w = w4.w, bs = b4.w;
                const size_t bq = base + 3 * (size_t)LFIN;
                if (ts < 1)   out[bq + ts] = fmaf(w, lds[ts], bs);
                if (ts < 255) {
                    float4 v = make_float4(fmaf(w, hv[1], bs), fmaf(w, hv[2], bs),
                                           fmaf(w, hv[3], bs), fmaf(w, hv[4], bs));
                    *reinterpret_cast<float4*>(&out[bq + 1 + 4 * ts]) = v;
                }
                if (ts < 3)   out[bq + 1021 + ts] = fmaf(w, lds[1021 + ts], bs);
            }
            base += 4 * (size_t)LFIN;
        }
    } else {
        // last tile: n_out == 1
        #pragma unroll 1
        for (int k = 0; k < 64; ++k) {
            const int c = cbase + k;
            const float w = ow[c], bs = ob[c];
            const size_t base = ((size_t)(b * NC + c)) * LFIN + s0;
            if (ts < n_out) out[base + ts] = fmaf(w, lds[ts], bs);
        }
    }
}

extern "C" void kernel_launch(void* const* d_in, const int* in_sizes, int n_in,
                              void* d_out, int out_size, void* d_ws, size_t ws_size,
                              hipStream_t stream) {
    const float* x  = (const float*)d_in[0];
    const float* cw = (const float*)d_in[1];
    const float* cb = (const float*)d_in[2];
    const float* ow = (const float*)d_in[3];
    const float* ob = (const float*)d_in[4];
    float* out = (float*)d_out;
    (void)d_ws; (void)ws_size; (void)in_sizes; (void)n_in; (void)out_size;

    wn_fat<<<B_ * TILES, 1024, 0, stream>>>(x, cw, cb, ow, ob, out);
}